// Round 6
// baseline (247.643 us; speedup 1.0000x reference)
//
#include <hip/hip_runtime.h>
#include <hip/hip_bf16.h>
#include <stdint.h>

// Problem constants (B=4, L=4096, D=1024, K=3)
#define B_SZ   4
#define L_SEQ  4096
#define D_DIM  1024
#define M_TOT  (B_SZ * L_SEQ)   // 16384

typedef __bf16 bf16;
typedef __attribute__((ext_vector_type(8))) __bf16 bf16x8;
typedef __attribute__((ext_vector_type(4))) float   f32x4;

#define GLOAD_LDS16(g, l)                                                     \
  __builtin_amdgcn_global_load_lds(                                           \
      (const __attribute__((address_space(1))) void*)(g),                     \
      (__attribute__((address_space(3))) void*)(l), 16, 0, 0)

// ---------------------------------------------------------------------------
// Kernel 1: w_pw fp32 -> bf16 (1024x1024), 512 blocks, ~3us.
// ---------------------------------------------------------------------------
__global__ __launch_bounds__(256) void cvt_bf16_kernel(
    const float* __restrict__ w, bf16* __restrict__ o) {
  int i = (blockIdx.x * 256 + threadIdx.x) * 8;
  float4 a = *(const float4*)(w + i);
  float4 b = *(const float4*)(w + i + 4);
  union { bf16 h[8]; int4 v; } r;
  r.h[0] = (bf16)a.x; r.h[1] = (bf16)a.y; r.h[2] = (bf16)a.z; r.h[3] = (bf16)a.w;
  r.h[4] = (bf16)b.x; r.h[5] = (bf16)b.y; r.h[6] = (bf16)b.z; r.h[7] = (bf16)b.w;
  *(int4*)(o + i) = r.v;
}

// ---------------------------------------------------------------------------
// Kernel 2: FUSED causal-dw-conv + GEMM.
//   out[m][n] = sum_d dw(x)[m][d] * w_pw[n][d] + b_pw[n]
// GEMM core = round-2 exact (measured best, 54.4us): BM=BN=128, BK=64,
// single 32KB LDS buffer, 2 barriers/tile; grid (m=x fastest) -> XCD=mb%8.
// A-tile is NOT read from a y buffer: each block computes dw(x) for its
// 128 rows x 64 chans per K-iter in-register and ds_writes bf16 into the
// swizzled A layout. Kills the separate dw kernel + y's 96MB HBM round-trip.
// A-staging thread map: g=t&15 (4 chans), rt=t>>4 (8 rows): 10 float4 x
// loads (2 halo, predicated at batch start), 8 fma-triples, 8 ds_write_b64
// (each row's 16 lanes span all 32 banks -> pure-throughput, no conflict).
// B-staging: global_load_lds w=16, XOR-swizzled (r2-exact).
// Epilogue: per-wave LDS transpose -> float4 stores (r2-exact, 64MB writes).
// ---------------------------------------------------------------------------
#define BM 128
#define BN 128
#define BK 64
#define EP_ROWP 68   // fp32 per padded epilogue row

__global__ __launch_bounds__(256, 3) void fused_dw_gemm_kernel(
    const float* __restrict__ x,     // (B*L) x D fp32
    const float* __restrict__ w_dw,  // D x 3 fp32
    const float* __restrict__ b_dw,  // D fp32
    const bf16* __restrict__ Bw,     // N x K row-major (w_pw bf16)
    const float* __restrict__ bias,  // b_pw
    float* __restrict__ C) {
  __shared__ __align__(16) char smem[32768];  // A 16KB | B 16KB

  const int t    = threadIdx.x;
  const int m0   = blockIdx.x * BM;   // grid.x = 128 (m) — fastest
  const int n0   = blockIdx.y * BN;   // grid.y = 8   (n)
  const int lane = t & 63;
  const int wv   = t >> 6;
  const int wm   = (wv >> 1) * 64;
  const int wn   = (wv & 1) * 64;
  const int lrow = lane & 15;
  const int q    = lane >> 4;

  f32x4 acc[4][4] = {};

  // ---- B staging geometry (r2-exact) ----
  int goffB[4];
#pragma unroll
  for (int i = 0; i < 4; ++i) {
    int s   = i * 256 + t;
    int row = s >> 3;
    int gc  = (s & 7) ^ (row & 7);
    goffB[i] = row * (D_DIM * 2) + gc * 16;   // bytes
  }
  const char* pB = (const char*)(Bw + (size_t)n0 * D_DIM);
  const unsigned lbase = (unsigned)(wv * 1024);

  // ---- A staging (fused dw) geometry ----
  const int g  = t & 15;        // float4 channel group within BK (4 chans)
  const int rt = t >> 4;        // 8-row slice: rows rt*8 .. rt*8+7
  const float* xp = x + (size_t)(m0 + rt * 8) * D_DIM + g * 4;
  const bool halo_ok = ((m0 & (L_SEQ - 1)) != 0) || (rt != 0);
  // LDS write offsets: row m=rt*8+j, chunk c8=g>>1 swizzled by (m&7), half g&1
  int awoff[8];
#pragma unroll
  for (int j = 0; j < 8; ++j) {
    int m = rt * 8 + j;
    awoff[j] = m * 128 + (((g >> 1) ^ (m & 7)) * 16) + ((g & 1) * 8);
  }

  // ---- fragment LDS byte offsets (kk=0); kk=1 = ^64 ----
  int aoff[4], boff[4];
#pragma unroll
  for (int i = 0; i < 4; ++i) {
    int mrow = wm + i * 16 + lrow;
    aoff[i] = mrow * 128 + ((q ^ (mrow & 7)) * 16);
    int nrow = wn + i * 16 + lrow;
    boff[i] = 16384 + nrow * 128 + ((q ^ (nrow & 7)) * 16);
  }

  const float4 zero = make_float4(0.f, 0.f, 0.f, 0.f);

  for (int it = 0; it < D_DIM / BK; ++it) {
    const int k0 = it * BK;
    __syncthreads();                 // previous tile's LDS reads complete

    // --- B: async DMA (16KB) ---
#pragma unroll
    for (int i = 0; i < 4; ++i)
      GLOAD_LDS16(pB + goffB[i], smem + 16384 + (unsigned)(i * 4096) + lbase);

    // --- A: load x slice, dw-conv, cast, ds_write ---
    float4 xr[10];
    xr[0] = halo_ok ? *(const float4*)(xp + k0 - 2 * D_DIM) : zero;
    xr[1] = halo_ok ? *(const float4*)(xp + k0 - 1 * D_DIM) : zero;
#pragma unroll
    for (int h = 0; h < 8; ++h)
      xr[h + 2] = *(const float4*)(xp + k0 + h * D_DIM);

    const float* wq = w_dw + (size_t)(k0 + g * 4) * 3;   // 12 contiguous floats
    float4 wa = *(const float4*)(wq);
    float4 wb = *(const float4*)(wq + 4);
    float4 wc = *(const float4*)(wq + 8);
    float4 bv = *(const float4*)(b_dw + k0 + g * 4);

#pragma unroll
    for (int j = 0; j < 8; ++j) {
      float4 x2 = xr[j], x1 = xr[j + 1], x0 = xr[j + 2];
      float a0 = fmaf(x2.x, wa.x, fmaf(x1.x, wa.y, fmaf(x0.x, wa.z, bv.x)));
      float a1 = fmaf(x2.y, wa.w, fmaf(x1.y, wb.x, fmaf(x0.y, wb.y, bv.y)));
      float a2 = fmaf(x2.z, wb.z, fmaf(x1.z, wb.w, fmaf(x0.z, wc.x, bv.z)));
      float a3 = fmaf(x2.w, wc.y, fmaf(x1.w, wc.z, fmaf(x0.w, wc.w, bv.w)));
      union { bf16 h[4]; int2 v; } o;
      o.h[0] = (bf16)a0; o.h[1] = (bf16)a1; o.h[2] = (bf16)a2; o.h[3] = (bf16)a3;
      *(int2*)(smem + awoff[j]) = o.v;
    }
    pB += BK * 2;
    __syncthreads();                 // drains B-DMA (vmcnt) + A writes (lgkm)

    // --- compute: 2 x (8 frag loads + 16 MFMA) ---
#pragma unroll
    for (int kk = 0; kk < 2; ++kk) {
      const int xo = kk * 64;
      bf16x8 af[4], bfr[4];
#pragma unroll
      for (int i = 0; i < 4; ++i) {
        af[i]  = *(const bf16x8*)(smem + (aoff[i] ^ xo));
        bfr[i] = *(const bf16x8*)(smem + (boff[i] ^ xo));
      }
#pragma unroll
      for (int i = 0; i < 4; ++i)
#pragma unroll
        for (int j = 0; j < 4; ++j)
          acc[i][j] = __builtin_amdgcn_mfma_f32_16x16x32_bf16(af[i], bfr[j], acc[i][j], 0, 0, 0);
    }
  }

  // --- epilogue: per-wave LDS transpose, then coalesced float4 stores ---
  __syncthreads();   // all waves done reading staging buffers
  float* ep = (float*)smem + (size_t)wv * (16 * EP_ROWP);  // wave-private

  float bvj[4];
#pragma unroll
  for (int j = 0; j < 4; ++j) bvj[j] = bias[n0 + wn + j * 16 + lrow];

#pragma unroll
  for (int i = 0; i < 4; ++i) {
#pragma unroll
    for (int j = 0; j < 4; ++j)
#pragma unroll
      for (int r = 0; r < 4; ++r)
        ep[(q * 4 + r) * EP_ROWP + j * 16 + lrow] = acc[i][j][r] + bvj[j];
#pragma unroll
    for (int s = 0; s < 4; ++s) {
      int flat = s * 64 + lane;
      int row  = flat >> 4;
      int c4   = flat & 15;
      float4 v = *(const float4*)(ep + row * EP_ROWP + c4 * 4);
      int gm = m0 + wm + i * 16 + row;
      int gn = n0 + wn + c4 * 4;
      *(float4*)(C + (size_t)gm * D_DIM + gn) = v;
    }
    __syncthreads();  // r2-exact lockstep (r2 measured WRITE=64MB with this)
  }
}

// ---------------------------------------------------------------------------
// Fallback (only if workspace is too small): correct but slow fp32 path.
// ---------------------------------------------------------------------------
__global__ __launch_bounds__(256) void fallback_kernel(
    const float* __restrict__ x, const float* __restrict__ w_dw,
    const float* __restrict__ b_dw, const float* __restrict__ w_pw,
    const float* __restrict__ b_pw, float* __restrict__ out) {
  __shared__ float ys[D_DIM];
  const int m = blockIdx.x;
  const int l = m & (L_SEQ - 1);
  const int t = threadIdx.x;
  const float* xr = x + (size_t)m * D_DIM;
#pragma unroll
  for (int c = 0; c < 4; ++c) {
    int d = t + c * 256;
    float a = fmaf(xr[d], w_dw[d * 3 + 2], b_dw[d]);
    if (l >= 1) a = fmaf(xr[d - D_DIM], w_dw[d * 3 + 1], a);
    if (l >= 2) a = fmaf(xr[d - 2 * D_DIM], w_dw[d * 3 + 0], a);
    ys[d] = a;
  }
  __syncthreads();
#pragma unroll
  for (int c = 0; c < 4; ++c) {
    int e = t + c * 256;
    const float* wr = w_pw + (size_t)e * D_DIM;
    float a = b_pw[e];
    for (int d = 0; d < D_DIM; ++d) a = fmaf(ys[d], wr[d], a);
    out[(size_t)m * D_DIM + e] = a;
  }
}

extern "C" void kernel_launch(void* const* d_in, const int* in_sizes, int n_in,
                              void* d_out, int out_size, void* d_ws, size_t ws_size,
                              hipStream_t stream) {
  (void)in_sizes; (void)n_in; (void)out_size;
  const float* x    = (const float*)d_in[0];
  const float* w_dw = (const float*)d_in[1];
  const float* b_dw = (const float*)d_in[2];
  const float* w_pw = (const float*)d_in[3];
  const float* b_pw = (const float*)d_in[4];
  float* out = (float*)d_out;

  const size_t w_elems = (size_t)D_DIM * D_DIM;   // 1M bf16 = 2 MB
  if (ws_size >= w_elems * sizeof(bf16)) {
    bf16* wpwb = (bf16*)d_ws;
    cvt_bf16_kernel<<<(D_DIM * D_DIM / 8) / 256, 256, 0, stream>>>(w_pw, wpwb);
    dim3 grid(M_TOT / BM, D_DIM / BN);            // (128, 8): m fastest
    fused_dw_gemm_kernel<<<grid, 256, 0, stream>>>(x, w_dw, b_dw, wpwb, b_pw, out);
  } else {
    fallback_kernel<<<M_TOT, 256, 0, stream>>>(x, w_dw, b_dw, w_pw, b_pw, out);
  }
}